// Round 3
// baseline (39.957 us; speedup 1.0000x reference)
//
#include <hip/hip_runtime.h>
#include <math.h>

// p = sigmoid(x); lp = log p = x - softplus(x); l01 = log p + log(1-p) = x - 2*softplus(x)
__device__ __forceinline__ void sig_terms(float x, float& p, float& lp, float& l01) {
    float e  = __expf(-fabsf(x));            // e^{-|x|} in (0,1]
    float u  = 1.0f + e;
    float s  = fmaxf(x, 0.0f) + __logf(u);   // softplus(x)
    float ru = __builtin_amdgcn_rcpf(u);
    p   = ((x >= 0.0f) ? 1.0f : e) * ru;
    lp  = x - s;
    l01 = x - 2.0f * s;
}

__device__ __forceinline__ float sigmoid_only(float x) {
    float e  = __expf(-fabsf(x));
    float u  = 1.0f + e;
    float ru = __builtin_amdgcn_rcpf(u);
    return ((x >= 0.0f) ? 1.0f : e) * ru;
}

// One block per row (N = 4096). 4 waves x 1024-elem contiguous segments.
// Within a segment: 4 chunks of 256; lane l owns float4 at seg + 256c + 4l.
// Neighbors: in-register + in-wave shuffles; NO row LDS, NO mid-kernel barrier.
__global__ __launch_bounds__(256) void row_loss_kernel(
        const float* __restrict__ in,
        const float* __restrict__ tgt,
        float* __restrict__ row_out,
        float invN) {
    constexpr int N = 4096;
    const int b = blockIdx.x;
    const float* __restrict__ row = in + (size_t)b * N;
    const int t = threadIdx.x;
    const int w = t >> 6;          // wave 0..3
    const int l = t & 63;          // lane
    const int seg = w << 10;       // segment start (1024 per wave)

    // Wave-uniform boundary p values (scalar/SMEM loads; 0-padding at row ends).
    float pl_wave = 0.0f, pr_wave = 0.0f;
    if (seg > 0)        pl_wave = sigmoid_only(row[seg - 1]);
    if (seg + 1024 < N) pr_wave = sigmoid_only(row[seg + 1024]);

    float accH = 0.0f;   // sum p*(p_left+p_right)*logp
    float accL = 0.0f;   // sum (logp + log(1-p))
    float prev_p3 = 0.0f;
    float dc = 0.0f;     // deferred lane-63 coefficient p3*lp3

#pragma unroll
    for (int c = 0; c < 4; ++c) {
        const int idx = seg + (c << 8) + (l << 2);
        float4 v = *reinterpret_cast<const float4*>(row + idx);

        float p0, p1, p2, p3, lp0, lp1, lp2, lp3, q;
        sig_terms(v.x, p0, lp0, q); accL += q;
        sig_terms(v.y, p1, lp1, q); accL += q;
        sig_terms(v.z, p2, lp2, q); accL += q;
        sig_terms(v.w, p3, lp3, q); accL += q;

        // Resolve previous chunk's lane-63 deferred right-neighbor term:
        // its right neighbor is this chunk's lane-0 p0.
        float b0 = __shfl(p0, 0);
        accH += dc * b0;

        // In-wave neighbor exchange.
        float leftP  = __shfl_up(p3, 1);          // lane l-1's p3
        float rightP = __shfl_down(p0, 1);        // lane l+1's p0
        if (l == 0)  leftP  = (c == 0) ? pl_wave : __shfl(prev_p3, 63);
        if (l == 63) rightP = 0.0f;               // deferred below

        accH += p0 * (leftP + p1) * lp0;
        accH += p1 * (p0 + p2)    * lp1;
        accH += p2 * (p1 + p3)    * lp2;
        accH += p3 * (p2 + rightP)* lp3;

        dc = (l == 63) ? p3 * lp3 : 0.0f;
        prev_p3 = p3;
    }
    // Last chunk's lane-63 right neighbor is the wave-right boundary p.
    accH += dc * pr_wave;

    float acc = accH + invN * accL;

    // Wave shuffle reduce, then 4-value cross-wave reduce.
#pragma unroll
    for (int off = 32; off > 0; off >>= 1) acc += __shfl_down(acc, off);

    __shared__ float sm[4];
    if (l == 0) sm[w] = acc;
    __syncthreads();
    if (t == 0) {
        row_out[b] = -tgt[b] * (sm[0] + sm[1] + sm[2] + sm[3]);
    }
}

// Deterministic mean over B row losses -> single scalar. float4 loads.
__global__ __launch_bounds__(1024) void reduce_mean_kernel(
        const float* __restrict__ row_loss, float* __restrict__ out,
        int B, float invB) {
    const int nvec = B >> 2;
    float acc = 0.0f;
    for (int i = threadIdx.x; i < nvec; i += 1024) {
        float4 v = reinterpret_cast<const float4*>(row_loss)[i];
        acc += (v.x + v.y) + (v.z + v.w);
    }
#pragma unroll
    for (int off = 32; off > 0; off >>= 1) acc += __shfl_down(acc, off);
    __shared__ float sm[16];
    if ((threadIdx.x & 63) == 0) sm[threadIdx.x >> 6] = acc;
    __syncthreads();
    if (threadIdx.x == 0) {
        float s = 0.0f;
#pragma unroll
        for (int wv = 0; wv < 16; ++wv) s += sm[wv];
        out[0] = s * invB;
    }
}

extern "C" void kernel_launch(void* const* d_in, const int* in_sizes, int n_in,
                              void* d_out, int out_size, void* d_ws, size_t ws_size,
                              hipStream_t stream) {
    const float* inputs  = (const float*)d_in[0];
    const float* targets = (const float*)d_in[1];
    float* out = (float*)d_out;

    const int B = in_sizes[1];
    const int N = in_sizes[0] / B;  // 4096

    float* row_loss = (float*)d_ws;  // B floats of scratch

    row_loss_kernel<<<B, 256, 0, stream>>>(inputs, targets, row_loss, 1.0f / (float)N);
    reduce_mean_kernel<<<1, 1024, 0, stream>>>(row_loss, out, B, 1.0f / (float)B);
}